// Round 2
// baseline (69.832 us; speedup 1.0000x reference)
//
#include <hip/hip_runtime.h>

// Barnes-Wall Lambda16 quantizer.
// One thread per input row (16 floats). 32 coset candidates per row:
//   diff = x - c;  f = D2-quantize(diff) (round-half-even, parity fix on the
//   worst coordinate);  X = 2f + c;  D = ||X - x||^2 ; pick first argmin.
// Bit-exactness notes (argmin flips cost >= a ~ 0.5 in absmax, so every f32
// op must match the numpy reference):
//  - fp contract OFF (numpy has no FMA)
//  - rintf == round-half-to-even == v_rndne_f32 == np.round
//  - D summed in numpy's pairwise order for n=16:
//      r[j] = sq[j] + sq[j+8];  D = ((r0+r1)+(r2+r3)) + ((r4+r5)+(r6+r7))
//  - argmax/argmin: first occurrence wins (strict compare)

__global__ __launch_bounds__(256) void bw_quant_kernel(
    const float* __restrict__ x_in,
    const float* __restrict__ C_rep,
    const float* __restrict__ a_ptr,
    float* __restrict__ y_out,
    int n_rows)
{
#pragma clang fp contract(off)
    __shared__ float Cs[32][16];
    const int tid = threadIdx.x;
    // Stage the 2KB codebook in LDS once per block.
    for (int i = tid; i < 32 * 16; i += 256) {
        Cs[i >> 4][i & 15] = C_rep[i];
    }
    __syncthreads();

    const int row = blockIdx.x * 256 + tid;
    if (row >= n_rows) return;

    const float a = a_ptr[0];

    // Vectorized row load (rows are 64B-aligned).
    float x[16];
    {
        const float4* xr4 = reinterpret_cast<const float4*>(x_in + (size_t)row * 16);
        #pragma unroll
        for (int q = 0; q < 4; ++q) {
            float4 v = xr4[q];
            x[q * 4 + 0] = v.x / a;
            x[q * 4 + 1] = v.y / a;
            x[q * 4 + 2] = v.z / a;
            x[q * 4 + 3] = v.w / a;
        }
    }

    float bestD = __builtin_inff();
    float bestX[16];
    #pragma unroll
    for (int j = 0; j < 16; ++j) bestX[j] = 0.0f;

    #pragma unroll 1
    for (int k = 0; k < 32; ++k) {
        float f[16];
        int par = 0;
        float rbest = -1.0f;
        float xc = 0.0f, fc = 0.0f;
        int col = 0;
        #pragma unroll
        for (int j = 0; j < 16; ++j) {
            float x2 = (x[j] - Cs[k][j]) * 0.5f;
            float fj = rintf(x2);             // round-half-to-even
            f[j] = fj;
            par += (int)fj;                   // exact: fj is integer-valued
            float r = fabsf(x2 - fj);
            if (r > rbest) {                  // strict > : first max wins
                rbest = r; col = j; xc = x2; fc = fj;
            }
        }
        if (par & 1) {
            float corr = (ceilf(xc) + floorf(xc)) - fc;  // flip rounding dir
            #pragma unroll
            for (int j = 0; j < 16; ++j)
                if (j == col) f[j] = corr;    // static-index select chain
        }

        float Xc[16];
        float sq[16];
        #pragma unroll
        for (int j = 0; j < 16; ++j) {
            float X = 2.0f * f[j] + Cs[k][j]; // (2f) + c, no FMA
            Xc[j] = X;
            float e = X - x[j];
            sq[j] = e * e;
        }
        // numpy pairwise-sum order for n=16
        float r0 = sq[0] + sq[8],  r1 = sq[1] + sq[9];
        float r2 = sq[2] + sq[10], r3 = sq[3] + sq[11];
        float r4 = sq[4] + sq[12], r5 = sq[5] + sq[13];
        float r6 = sq[6] + sq[14], r7 = sq[7] + sq[15];
        float D = ((r0 + r1) + (r2 + r3)) + ((r4 + r5) + (r6 + r7));

        if (D < bestD) {                      // strict < : first min wins
            bestD = D;
            #pragma unroll
            for (int j = 0; j < 16; ++j) bestX[j] = Xc[j];
        }
    }

    float4* yr4 = reinterpret_cast<float4*>(y_out + (size_t)row * 16);
    #pragma unroll
    for (int q = 0; q < 4; ++q) {
        float4 v;
        v.x = bestX[q * 4 + 0] * a;
        v.y = bestX[q * 4 + 1] * a;
        v.z = bestX[q * 4 + 2] * a;
        v.w = bestX[q * 4 + 3] * a;
        yr4[q] = v;
    }
}

extern "C" void kernel_launch(void* const* d_in, const int* in_sizes, int n_in,
                              void* d_out, int out_size, void* d_ws, size_t ws_size,
                              hipStream_t stream) {
    const float* x_in  = (const float*)d_in[0];
    const float* C_rep = (const float*)d_in[1];
    const float* a_ptr = (const float*)d_in[2];
    float* y_out = (float*)d_out;

    const int n_rows = in_sizes[0] / 16;
    const int block = 256;
    const int grid = (n_rows + block - 1) / block;
    bw_quant_kernel<<<grid, block, 0, stream>>>(x_in, C_rep, a_ptr, y_out, n_rows);
}